// Round 4
// baseline (798.039 us; speedup 1.0000x reference)
//
#include <hip/hip_runtime.h>
#include <math.h>

#define NN    8
#define CC    256
#define HWHW  16384
#define NBOX  20

constexpr float C_ALPHA = 1e-3f, C_BETA = 5e-4f, C_GAMMA = 1e-3f, C_LAMB = 5e-6f;
constexpr float C_LN_EPS = 1e-5f;

// ws layout (float offsets)
#define OFF_FEA_S   0          // [N*HW] atomically combined (memset 0); stays fea_S
#define OFF_FEA_T   131072     // after k3_mid: per-pixel wcomb
#define OFF_CM_S    262144     // after k3_mid: per-pixel sms
#define OFF_CM_T    393216     // after k3_mid: per-pixel smt
#define OFF_MFG     524288     // [N*HW]
#define OFF_PCHS    655360     // [N*C*64] per-pixblock channel partials
#define OFF_PCHT    786432
#define OFF_PD      917504
#define OFF_PCTXS   1048576
#define OFF_PCTXT   1179648
#define OFF_CATT    1310720    // [N*C]
#define OFF_DSUM    1312768
#define OFF_SCAL    1314816    // [8] 0: sum(S-T)^2, 1: fg/bg, 2: mask loss
#define OFF_Y       1314824    // [16*128]
#define OFF_RELAP   1316872    // [8]

// ---- wave-64 reductions via DPP ----
__device__ __forceinline__ float dpp_wave_sum(float x) {
#define DPPADD(ctrl, rm) \
  x += __int_as_float(__builtin_amdgcn_update_dpp(0, __float_as_int(x), ctrl, rm, 0xf, true));
  DPPADD(0x111, 0xf)
  DPPADD(0x112, 0xf)
  DPPADD(0x114, 0xf)
  DPPADD(0x118, 0xf)
  DPPADD(0x142, 0xa)
  DPPADD(0x143, 0xc)
#undef DPPADD
  return x;  // total in lane 63
}

__device__ __forceinline__ float dpp_wave_max(float x) {
#define DPPMAX(ctrl, rm) { \
  int r_ = __builtin_amdgcn_update_dpp(__float_as_int(x), __float_as_int(x), ctrl, rm, 0xf, false); \
  x = fmaxf(x, __int_as_float(r_)); }
  DPPMAX(0x111, 0xf)
  DPPMAX(0x112, 0xf)
  DPPMAX(0x114, 0xf)
  DPPMAX(0x118, 0xf)
  DPPMAX(0x142, 0xa)
  DPPMAX(0x143, 0xc)
#undef DPPMAX
  return x;
}

// 1024-thread (16-wave) block reductions
__device__ __forceinline__ float blk_sum16(float v, float* scr) {
  int tid = threadIdx.x;
  v = dpp_wave_sum(v);
  if ((tid & 63) == 63) scr[tid >> 6] = v;
  __syncthreads();
  float r = 0.f;
#pragma unroll
  for (int i = 0; i < 16; i++) r += scr[i];
  __syncthreads();
  return r;
}
__device__ __forceinline__ float blk_max16(float v, float* scr) {
  int tid = threadIdx.x;
  v = dpp_wave_max(v);
  if ((tid & 63) == 63) scr[tid >> 6] = v;
  __syncthreads();
  float r = -1e30f;
#pragma unroll
  for (int i = 0; i < 16; i++) r = fmaxf(r, scr[i]);
  __syncthreads();
  return r;
}

__device__ __forceinline__ float block_sum256(float v, float* sm) {
  int tid = threadIdx.x;
  v = dpp_wave_sum(v);
  if ((tid & 63) == 63) sm[tid >> 6] = v;
  __syncthreads();
  float r = sm[0] + sm[1] + sm[2] + sm[3];
  __syncthreads();
  return r;
}

// ---- K1: pass 1. grid (64 pb, 4 cq, 8 n) x 256 thr.
// wave = 16-channel slice; lane owns 4 pixels; channel-pair software pipeline.
__global__ __launch_bounds__(256, 8) void k1_pass1(
    const float* __restrict__ S, const float* __restrict__ T,
    const float* __restrict__ w_ms, const float* __restrict__ w_mt,
    float* __restrict__ ws) {
  int tid = threadIdx.x;
  int lane = tid & 63, wv = tid >> 6;
  int pb = blockIdx.x, cq = blockIdx.y, n = blockIdx.z;
  int pix0 = pb * 256 + lane * 4;
  int ch0 = cq * 64 + wv * 16;

  __shared__ float l_wS[64], l_wT[64];
  __shared__ float f_feaS[256], f_feaT[256], f_cmS[256], f_cmT[256];
  __shared__ float l_chS[64], l_chT[64], l_D[64];
  __shared__ float l_sq[4];

  if (tid < 64) {
    l_wS[tid] = w_ms[cq * 64 + tid];
    l_wT[tid] = w_mt[cq * 64 + tid];
  }
  f_feaS[tid] = 0.f; f_feaT[tid] = 0.f; f_cmS[tid] = 0.f; f_cmT[tid] = 0.f;
  __syncthreads();

  const float* baseS = S + (size_t)(n * CC + ch0) * HWHW + pix0;
  const float* baseT = T + (size_t)(n * CC + ch0) * HWHW + pix0;

  float fS0 = 0, fS1 = 0, fS2 = 0, fS3 = 0;
  float fT0 = 0, fT1 = 0, fT2 = 0, fT3 = 0;
  float cS0 = 0, cS1 = 0, cS2 = 0, cS3 = 0;
  float cT0 = 0, cT1 = 0, cT2 = 0, cT3 = 0;
  float sq = 0.f;

#define PROC1(s4, t4, cc_) { \
  float asx = fabsf(s4.x), asy = fabsf(s4.y), asz = fabsf(s4.z), asw = fabsf(s4.w); \
  float atx = fabsf(t4.x), aty = fabsf(t4.y), atz = fabsf(t4.z), atw = fabsf(t4.w); \
  fS0 += asx; fS1 += asy; fS2 += asz; fS3 += asw; \
  fT0 += atx; fT1 += aty; fT2 += atz; fT3 += atw; \
  float wS = l_wS[wv * 16 + (cc_)], wT = l_wT[wv * 16 + (cc_)]; \
  cS0 = fmaf(s4.x, wS, cS0); cS1 = fmaf(s4.y, wS, cS1); \
  cS2 = fmaf(s4.z, wS, cS2); cS3 = fmaf(s4.w, wS, cS3); \
  cT0 = fmaf(t4.x, wT, cT0); cT1 = fmaf(t4.y, wT, cT1); \
  cT2 = fmaf(t4.z, wT, cT2); cT3 = fmaf(t4.w, wT, cT3); \
  float dx = s4.x - t4.x, dy = s4.y - t4.y, dz = s4.z - t4.z, dw = s4.w - t4.w; \
  sq = fmaf(dx, dx, sq); sq = fmaf(dy, dy, sq); \
  sq = fmaf(dz, dz, sq); sq = fmaf(dw, dw, sq); \
  float cp = (asx + asy) + (asz + asw); \
  float tp = (atx + aty) + (atz + atw); \
  float dp = (dx + dy) + (dz + dw); \
  cp = dpp_wave_sum(cp); tp = dpp_wave_sum(tp); dp = dpp_wave_sum(dp); \
  if (lane == 63) { l_chS[wv * 16 + (cc_)] = cp; l_chT[wv * 16 + (cc_)] = tp; \
                    l_D[wv * 16 + (cc_)] = dp; } }

  float4 sA = *(const float4*)(baseS);
  float4 tA = *(const float4*)(baseT);
  float4 sB = *(const float4*)(baseS + HWHW);
  float4 tB = *(const float4*)(baseT + HWHW);
#pragma unroll
  for (int p = 0; p < 8; p++) {
    float4 s0 = sA, t0 = tA, s1 = sB, t1 = tB;
    if (p < 7) {
      const float* qS = baseS + (size_t)(2 * p + 2) * HWHW;
      const float* qT = baseT + (size_t)(2 * p + 2) * HWHW;
      sA = *(const float4*)(qS);
      tA = *(const float4*)(qT);
      sB = *(const float4*)(qS + HWHW);
      tB = *(const float4*)(qT + HWHW);
    }
    PROC1(s0, t0, 2 * p)
    PROC1(s1, t1, 2 * p + 1)
  }
#undef PROC1

  // combine per-pixel sums across 4 waves
  atomicAdd(&f_feaS[lane * 4 + 0], fS0); atomicAdd(&f_feaS[lane * 4 + 1], fS1);
  atomicAdd(&f_feaS[lane * 4 + 2], fS2); atomicAdd(&f_feaS[lane * 4 + 3], fS3);
  atomicAdd(&f_feaT[lane * 4 + 0], fT0); atomicAdd(&f_feaT[lane * 4 + 1], fT1);
  atomicAdd(&f_feaT[lane * 4 + 2], fT2); atomicAdd(&f_feaT[lane * 4 + 3], fT3);
  atomicAdd(&f_cmS[lane * 4 + 0], cS0); atomicAdd(&f_cmS[lane * 4 + 1], cS1);
  atomicAdd(&f_cmS[lane * 4 + 2], cS2); atomicAdd(&f_cmS[lane * 4 + 3], cS3);
  atomicAdd(&f_cmT[lane * 4 + 0], cT0); atomicAdd(&f_cmT[lane * 4 + 1], cT1);
  atomicAdd(&f_cmT[lane * 4 + 2], cT2); atomicAdd(&f_cmT[lane * 4 + 3], cT3);

  sq = dpp_wave_sum(sq);
  if (lane == 63) l_sq[wv] = sq;
  __syncthreads();

  int gp = n * HWHW + pb * 256 + tid;
  atomicAdd(&ws[OFF_FEA_S + gp], f_feaS[tid]);
  atomicAdd(&ws[OFF_FEA_T + gp], f_feaT[tid]);
  atomicAdd(&ws[OFF_CM_S + gp],  f_cmS[tid]);
  atomicAdd(&ws[OFF_CM_T + gp],  f_cmT[tid]);

  if (tid < 64) {
    int bo = (n * CC + cq * 64 + tid) * 64 + pb;
    ws[OFF_PCHS + bo] = l_chS[tid];
    ws[OFF_PCHT + bo] = l_chT[tid];
    ws[OFF_PD + bo]   = l_D[tid];
  }
  if (tid == 0)
    atomicAdd(&ws[OFF_SCAL + 0], l_sq[0] + l_sq[1] + l_sq[2] + l_sq[3]);
}

// ---- K3_mid: fused mask + softmax stats + per-pixel weights + channel softmax.
// grid 8 (one block per n) x 1024 thr, 16 px/thread.
__global__ __launch_bounds__(1024) void k3_mid(const float* __restrict__ gt,
                                               float* __restrict__ ws) {
  int tid = threadIdx.x, n = blockIdx.x;
  __shared__ float bx[NBOX][5];
  __shared__ float scr[16];
  __shared__ float l_cpart[3][4][256];

  if (tid < NBOX) {
    const float* g = gt + (n * NBOX + tid) * 4;
    float wmin = floorf(g[0] * 0.125f);
    float hmin = floorf(g[1] * 0.125f);
    float wmax = ceilf(g[2] * 0.125f);
    float hmax = ceilf(g[3] * 0.125f);
    bx[tid][0] = wmin; bx[tid][1] = hmin; bx[tid][2] = wmax; bx[tid][3] = hmax;
    bx[tid][4] = 1.0f / ((hmax + 1.0f - hmin) * (wmax + 1.0f - wmin));
  }
  __syncthreads();

  // ---- pass A: MFG + bg count + local maxes
  float mxFS = -1e30f, mxFT = -1e30f, mxCS = -1e30f, mxCT = -1e30f;
  float bg = 0.f;
#pragma unroll
  for (int s = 0; s < 4; s++) {
    int pix = (tid + s * 1024) * 4;
    float hf = (float)(pix >> 7);
    float wf = (float)(pix & 127);
    float b0 = 0, b1 = 0, b2 = 0, b3 = 0;
#pragma unroll
    for (int b = 0; b < NBOX; b++) {
      if (hf >= bx[b][1] && hf <= bx[b][3]) {
        float wmn = bx[b][0], wmx = bx[b][2], ar = bx[b][4];
        if (wf >= wmn && wf <= wmx) b0 = fmaxf(b0, ar);
        if (wf + 1.f >= wmn && wf + 1.f <= wmx) b1 = fmaxf(b1, ar);
        if (wf + 2.f >= wmn && wf + 2.f <= wmx) b2 = fmaxf(b2, ar);
        if (wf + 3.f >= wmn && wf + 3.f <= wmx) b3 = fmaxf(b3, ar);
      }
    }
    *(float4*)&ws[OFF_MFG + n * HWHW + pix] = make_float4(b0, b1, b2, b3);
    bg += (b0 > 0 ? 0.f : 1.f) + (b1 > 0 ? 0.f : 1.f) +
          (b2 > 0 ? 0.f : 1.f) + (b3 > 0 ? 0.f : 1.f);
    float4 fS = *(const float4*)&ws[OFF_FEA_S + n * HWHW + pix];
    float4 fT = *(const float4*)&ws[OFF_FEA_T + n * HWHW + pix];
    float4 cS = *(const float4*)&ws[OFF_CM_S + n * HWHW + pix];
    float4 cT = *(const float4*)&ws[OFF_CM_T + n * HWHW + pix];
    mxFS = fmaxf(mxFS, fmaxf(fmaxf(fS.x, fS.y), fmaxf(fS.z, fS.w)));
    mxFT = fmaxf(mxFT, fmaxf(fmaxf(fT.x, fT.y), fmaxf(fT.z, fT.w)));
    mxCS = fmaxf(mxCS, fmaxf(fmaxf(cS.x, cS.y), fmaxf(cS.z, cS.w)));
    mxCT = fmaxf(mxCT, fmaxf(fmaxf(cT.x, cT.y), fmaxf(cT.z, cT.w)));
  }
  bg = blk_sum16(bg, scr);
  float invbg = (bg > 0.f) ? 1.0f / bg : 1.0f;
  mxFS = blk_max16(mxFS, scr) * (1.0f / 128.0f);
  mxFT = blk_max16(mxFT, scr) * (1.0f / 128.0f);
  mxCS = blk_max16(mxCS, scr);
  mxCT = blk_max16(mxCT, scr);

  // ---- pass B: Z sums
  float zFS = 0, zFT = 0, zCS = 0, zCT = 0;
#pragma unroll
  for (int s = 0; s < 4; s++) {
    int pix = (tid + s * 1024) * 4;
    float4 fS = *(const float4*)&ws[OFF_FEA_S + n * HWHW + pix];
    float4 fT = *(const float4*)&ws[OFF_FEA_T + n * HWHW + pix];
    float4 cS = *(const float4*)&ws[OFF_CM_S + n * HWHW + pix];
    float4 cT = *(const float4*)&ws[OFF_CM_T + n * HWHW + pix];
    zFS += expf(fS.x * (1.f/128.f) - mxFS) + expf(fS.y * (1.f/128.f) - mxFS)
         + expf(fS.z * (1.f/128.f) - mxFS) + expf(fS.w * (1.f/128.f) - mxFS);
    zFT += expf(fT.x * (1.f/128.f) - mxFT) + expf(fT.y * (1.f/128.f) - mxFT)
         + expf(fT.z * (1.f/128.f) - mxFT) + expf(fT.w * (1.f/128.f) - mxFT);
    zCS += expf(cS.x - mxCS) + expf(cS.y - mxCS) + expf(cS.z - mxCS) + expf(cS.w - mxCS);
    zCT += expf(cT.x - mxCT) + expf(cT.y - mxCT) + expf(cT.z - mxCT) + expf(cT.w - mxCT);
  }
  zFS = blk_sum16(zFS, scr);
  zFT = blk_sum16(zFT, scr);
  zCS = blk_sum16(zCS, scr);
  zCT = blk_sum16(zCT, scr);
  float iZFS = 1.0f / zFS, iZFT = 1.0f / zFT, iZCS = 1.0f / zCS, iZCT = 1.0f / zCT;

  // ---- pass C: per-pixel wcomb/sms/smt (overwrite FEA_T/CM_S/CM_T) + mask loss
  float macc = 0.f;
#pragma unroll
  for (int s = 0; s < 4; s++) {
    int pix = (tid + s * 1024) * 4;
    float4 fS = *(const float4*)&ws[OFF_FEA_S + n * HWHW + pix];
    float4 fT = *(const float4*)&ws[OFF_FEA_T + n * HWHW + pix];
    float4 cS = *(const float4*)&ws[OFF_CM_S + n * HWHW + pix];
    float4 cT = *(const float4*)&ws[OFF_CM_T + n * HWHW + pix];
    float4 mf = *(const float4*)&ws[OFF_MFG + n * HWHW + pix];
    float4 wc, sms, smt;
    float pS, pT, mbg;
#define PXC(j, fs_, ft_, cs_, ct_, mf_) \
    pT = expf(ft_ * (1.f/128.f) - mxFT) * iZFT; \
    pS = expf(fs_ * (1.f/128.f) - mxFS) * iZFS; \
    macc += fabsf(pS - pT); \
    mbg = (mf_ > 0.f) ? 0.f : invbg; \
    wc.j = (float)HWHW * pT * (C_ALPHA * mf_ + C_BETA * mbg); \
    sms.j = expf(cs_ - mxCS) * iZCS; \
    smt.j = expf(ct_ - mxCT) * iZCT;
    PXC(x, fS.x, fT.x, cS.x, cT.x, mf.x)
    PXC(y, fS.y, fT.y, cS.y, cT.y, mf.y)
    PXC(z, fS.z, fT.z, cS.z, cT.z, mf.z)
    PXC(w, fS.w, fT.w, cS.w, cT.w, mf.w)
#undef PXC
    *(float4*)&ws[OFF_FEA_T + n * HWHW + pix] = wc;
    *(float4*)&ws[OFF_CM_S + n * HWHW + pix]  = sms;
    *(float4*)&ws[OFF_CM_T + n * HWHW + pix]  = smt;
  }
  macc = blk_sum16(macc, scr);
  if (tid == 0) atomicAdd(&ws[OFF_SCAL + 2], macc * (float)HWHW);

  // ---- channel phase: reduce PCH partials + channel softmax
  int c = tid & 255, qg = tid >> 8;
  float aS = 0, aT = 0, aD = 0;
  int cb = (n * CC + c) * 64 + qg * 16;
#pragma unroll
  for (int k = 0; k < 16; k += 4) {
    float4 x = *(const float4*)&ws[OFF_PCHS + cb + k];
    float4 y = *(const float4*)&ws[OFF_PCHT + cb + k];
    float4 z = *(const float4*)&ws[OFF_PD + cb + k];
    aS += (x.x + x.y) + (x.z + x.w);
    aT += (y.x + y.y) + (y.z + y.w);
    aD += (z.x + z.y) + (z.z + z.w);
  }
  l_cpart[0][qg][c] = aS;
  l_cpart[1][qg][c] = aT;
  l_cpart[2][qg][c] = aD;
  __syncthreads();

  bool act = tid < 256;
  float lS = -1e30f, lT = -1e30f;
  if (act) {
    float chS = l_cpart[0][0][tid] + l_cpart[0][1][tid] + l_cpart[0][2][tid] + l_cpart[0][3][tid];
    float chT = l_cpart[1][0][tid] + l_cpart[1][1][tid] + l_cpart[1][2][tid] + l_cpart[1][3][tid];
    float Dv  = l_cpart[2][0][tid] + l_cpart[2][1][tid] + l_cpart[2][2][tid] + l_cpart[2][3][tid];
    ws[OFF_DSUM + n * CC + tid] = Dv;
    lS = chS * (1.0f / 8192.0f);
    lT = chT * (1.0f / 8192.0f);
  }
  float mS = blk_max16(lS, scr);
  float mT = blk_max16(lT, scr);
  float eS = act ? expf(lS - mS) : 0.f;
  float eT = act ? expf(lT - mT) : 0.f;
  float ZS = blk_sum16(eS, scr);
  float ZT = blk_sum16(eT, scr);
  float mml = 0.f;
  if (act) {
    float cattS = (float)CC * eS / ZS;
    float cattT = (float)CC * eT / ZT;
    ws[OFF_CATT + n * CC + tid] = cattT;
    mml = fabsf(cattS - cattT);
  }
  mml = blk_sum16(mml, scr);
  if (tid == 0) atomicAdd(&ws[OFF_SCAL + 2], mml);
}

// ---- K4: pass 2. grid (64 pb, 4 cq, 8 n) x 256 thr, pipelined like k1.
__global__ __launch_bounds__(256, 8) void k4_pass2(
    const float* __restrict__ S, const float* __restrict__ T,
    float* __restrict__ ws) {
  int tid = threadIdx.x;
  int lane = tid & 63, wv = tid >> 6;
  int pb = blockIdx.x, cq = blockIdx.y, n = blockIdx.z;
  int pix0 = pb * 256 + lane * 4;
  int ch0 = cq * 64 + wv * 16;

  __shared__ float l_catt[64];
  __shared__ float wcombL[256], smsL[256], smtL[256];
  __shared__ float l_cs[64], l_ct[64], l_c[4];

  if (tid < 64) {
    l_catt[tid] = ws[OFF_CATT + n * CC + cq * 64 + tid];
    int gp = n * HWHW + pb * 256 + tid * 4;
    float4 wc = *(const float4*)&ws[OFF_FEA_T + gp];
    float4 a  = *(const float4*)&ws[OFF_CM_S + gp];
    float4 b  = *(const float4*)&ws[OFF_CM_T + gp];
    *(float4*)&wcombL[tid * 4] = wc;
    *(float4*)&smsL[tid * 4]   = a;
    *(float4*)&smtL[tid * 4]   = b;
  }
  __syncthreads();

  float4 sms4 = *(const float4*)&smsL[lane * 4];
  float4 smt4 = *(const float4*)&smtL[lane * 4];
  float4 wcb  = *(const float4*)&wcombL[lane * 4];

  const float* baseS = S + (size_t)(n * CC + ch0) * HWHW + pix0;
  const float* baseT = T + (size_t)(n * CC + ch0) * HWHW + pix0;

  float aw0 = 0, aw1 = 0, aw2 = 0, aw3 = 0;

#define PROC4(s4, t4, cc_) { \
  float ca = l_catt[wv * 16 + (cc_)]; \
  float dx = s4.x - t4.x, dy = s4.y - t4.y, dz = s4.z - t4.z, dw = s4.w - t4.w; \
  aw0 = fmaf(dx * dx, ca, aw0); aw1 = fmaf(dy * dy, ca, aw1); \
  aw2 = fmaf(dz * dz, ca, aw2); aw3 = fmaf(dw * dw, ca, aw3); \
  float xs = fmaf(s4.x, sms4.x, fmaf(s4.y, sms4.y, fmaf(s4.z, sms4.z, s4.w * sms4.w))); \
  float xt = fmaf(t4.x, smt4.x, fmaf(t4.y, smt4.y, fmaf(t4.z, smt4.z, t4.w * smt4.w))); \
  xs = dpp_wave_sum(xs); xt = dpp_wave_sum(xt); \
  if (lane == 63) { l_cs[wv * 16 + (cc_)] = xs; l_ct[wv * 16 + (cc_)] = xt; } }

  float4 sA = *(const float4*)(baseS);
  float4 tA = *(const float4*)(baseT);
  float4 sB = *(const float4*)(baseS + HWHW);
  float4 tB = *(const float4*)(baseT + HWHW);
#pragma unroll
  for (int p = 0; p < 8; p++) {
    float4 s0 = sA, t0 = tA, s1 = sB, t1 = tB;
    if (p < 7) {
      const float* qS = baseS + (size_t)(2 * p + 2) * HWHW;
      const float* qT = baseT + (size_t)(2 * p + 2) * HWHW;
      sA = *(const float4*)(qS);
      tA = *(const float4*)(qT);
      sB = *(const float4*)(qS + HWHW);
      tB = *(const float4*)(qT + HWHW);
    }
    PROC4(s0, t0, 2 * p)
    PROC4(s1, t1, 2 * p + 1)
  }
#undef PROC4

  float contrib = fmaf(aw0, wcb.x, fmaf(aw1, wcb.y, fmaf(aw2, wcb.z, aw3 * wcb.w)));
  contrib = dpp_wave_sum(contrib);
  if (lane == 63) l_c[wv] = contrib;
  __syncthreads();

  if (tid < 64) {
    int bo = (n * CC + cq * 64 + tid) * 64 + pb;
    ws[OFF_PCTXS + bo] = l_cs[tid];
    ws[OFF_PCTXT + bo] = l_ct[tid];
  }
  if (tid == 0)
    atomicAdd(&ws[OFF_SCAL + 1], l_c[0] + l_c[1] + l_c[2] + l_c[3]);
}

// ---- K5a: ctx reduce + GEMM1 + LN + ReLU. grid 16 (n*2+st) x 128 thr
__global__ __launch_bounds__(128) void k5a_mlp1(
    const float* __restrict__ w1_s, const float* __restrict__ b1_s,
    const float* __restrict__ g_s,  const float* __restrict__ be_s,
    const float* __restrict__ w1_t, const float* __restrict__ b1_t,
    const float* __restrict__ g_t,  const float* __restrict__ be_t,
    float* __restrict__ ws) {
  int tid = threadIdx.x;
  int n = blockIdx.x >> 1, st = blockIdx.x & 1;
  const float* w1 = st ? w1_t : w1_s;
  const float* b1 = st ? b1_t : b1_s;
  const float* g  = st ? g_t  : g_s;
  const float* be = st ? be_t : be_s;
  int poff = st ? OFF_PCTXT : OFF_PCTXS;

  __shared__ float ctx[CC];
  __shared__ float red[2];
  for (int c = tid; c < CC; c += 128) {
    float a = 0.f;
    int base = poff + (n * CC + c) * 64;
#pragma unroll
    for (int k = 0; k < 64; k += 4) {
      float4 x = *(const float4*)&ws[base + k];
      a += (x.x + x.y) + (x.z + x.w);
    }
    ctx[c] = a;
  }
  __syncthreads();

  float acc = b1[tid];
  const float* wr = w1 + tid * CC;
#pragma unroll 8
  for (int c = 0; c < CC; c += 4) {
    float4 w = *(const float4*)(wr + c);
    acc = fmaf(w.x, ctx[c], acc);
    acc = fmaf(w.y, ctx[c + 1], acc);
    acc = fmaf(w.z, ctx[c + 2], acc);
    acc = fmaf(w.w, ctx[c + 3], acc);
  }

  float v = dpp_wave_sum(acc);
  if ((tid & 63) == 63) red[tid >> 6] = v;
  __syncthreads();
  float mean = (red[0] + red[1]) * (1.0f / 128.0f);
  __syncthreads();
  float dm = acc - mean;
  v = dpp_wave_sum(dm * dm);
  if ((tid & 63) == 63) red[tid >> 6] = v;
  __syncthreads();
  float var = (red[0] + red[1]) * (1.0f / 128.0f);
  float q = dm * (1.0f / sqrtf(var + C_LN_EPS)) * g[tid] + be[tid];
  ws[OFF_Y + blockIdx.x * 128 + tid] = q > 0.f ? q : 0.f;
}

// ---- K5b: GEMM2 + rela cross terms. grid 8 x 256
__global__ __launch_bounds__(256) void k5b_mlp2(
    const float* __restrict__ w2_s, const float* __restrict__ b2_s,
    const float* __restrict__ w2_t, const float* __restrict__ b2_t,
    float* __restrict__ ws) {
  int tid = threadIdx.x, n = blockIdx.x;
  __shared__ float ysh[128], yth[128];
  __shared__ float sm[4];
  if (tid < 128) ysh[tid] = ws[OFF_Y + (n * 2 + 0) * 128 + tid];
  else           yth[tid - 128] = ws[OFF_Y + (n * 2 + 1) * 128 + (tid - 128)];
  __syncthreads();

  float es = b2_s[tid], et = b2_t[tid];
  const float* w2sr = w2_s + tid * 128;
  const float* w2tr = w2_t + tid * 128;
#pragma unroll 8
  for (int j = 0; j < 128; j += 4) {
    float4 a = *(const float4*)(w2sr + j);
    float4 b = *(const float4*)(w2tr + j);
    es = fmaf(a.x, ysh[j], es); es = fmaf(a.y, ysh[j + 1], es);
    es = fmaf(a.z, ysh[j + 2], es); es = fmaf(a.w, ysh[j + 3], es);
    et = fmaf(b.x, yth[j], et); et = fmaf(b.y, yth[j + 1], et);
    et = fmaf(b.z, yth[j + 2], et); et = fmaf(b.w, yth[j + 3], et);
  }
  float e = es - et;
  float rp = 2.0f * e * ws[OFF_DSUM + n * CC + tid] + (float)HWHW * e * e;
  rp = block_sum256(rp, sm);
  if (tid == 0) ws[OFF_RELAP + n] = rp;
}

// ---- K5c: final combine. 1 block x 64
__global__ __launch_bounds__(64) void k5c_final(float* __restrict__ ws,
                                                float* __restrict__ out) {
  int lane = threadIdx.x;
  float r = (lane < NN) ? ws[OFF_RELAP + lane] : 0.f;
  r = dpp_wave_sum(r);
  if (lane == 63) {
    float rela = ws[OFF_SCAL + 0] + r;
    out[0] = (ws[OFF_SCAL + 1] + C_GAMMA * ws[OFF_SCAL + 2] + C_LAMB * rela) *
             (1.0f / (float)NN);
  }
}

extern "C" void kernel_launch(void* const* d_in, const int* in_sizes, int n_in,
                              void* d_out, int out_size, void* d_ws, size_t ws_size,
                              hipStream_t stream) {
  const float* S    = (const float*)d_in[0];
  const float* T    = (const float*)d_in[1];
  const float* gt   = (const float*)d_in[2];
  const float* w_ms = (const float*)d_in[3];
  const float* w_mt = (const float*)d_in[5];
  const float* w1_s = (const float*)d_in[7];
  const float* b1_s = (const float*)d_in[8];
  const float* g_s  = (const float*)d_in[9];
  const float* be_s = (const float*)d_in[10];
  const float* w2_s = (const float*)d_in[11];
  const float* b2_s = (const float*)d_in[12];
  const float* w1_t = (const float*)d_in[13];
  const float* b1_t = (const float*)d_in[14];
  const float* g_t  = (const float*)d_in[15];
  const float* be_t = (const float*)d_in[16];
  const float* w2_t = (const float*)d_in[17];
  const float* b2_t = (const float*)d_in[18];
  float* ws = (float*)d_ws;
  float* out = (float*)d_out;

  // zero per-pixel atomic-accumulation arrays (FEA/CM) + SCAL scalars
  hipMemsetAsync(ws, 0, 524288 * sizeof(float), stream);
  hipMemsetAsync(ws + OFF_SCAL, 0, 8 * sizeof(float), stream);

  k1_pass1<<<dim3(64, 4, 8), dim3(256), 0, stream>>>(S, T, w_ms, w_mt, ws);
  k3_mid<<<dim3(8), dim3(1024), 0, stream>>>(gt, ws);
  k4_pass2<<<dim3(64, 4, 8), dim3(256), 0, stream>>>(S, T, ws);
  k5a_mlp1<<<dim3(16), dim3(128), 0, stream>>>(w1_s, b1_s, g_s, be_s,
                                               w1_t, b1_t, g_t, be_t, ws);
  k5b_mlp2<<<dim3(8), dim3(256), 0, stream>>>(w2_s, b2_s, w2_t, b2_t, ws);
  k5c_final<<<dim3(1), dim3(64), 0, stream>>>(ws, out);
}